// Round 1
// 788.765 us; speedup vs baseline: 1.0087x; 1.0087x over previous
//
#include <hip/hip_runtime.h>
#include <stdint.h>
#include <math.h>

#define NTOK 16384
#define HID  2048
#define NGRP 16          // HID/128
#define EPSF 1e-5f

typedef __bf16 bf16;
typedef __bf16 bf16x8 __attribute__((ext_vector_type(8)));
typedef float  f32x4  __attribute__((ext_vector_type(4)));

// ---------------- helpers ----------------

__device__ __forceinline__ void async_load16(const void* g, void* l) {
  __builtin_amdgcn_global_load_lds((const __attribute__((address_space(1))) void*)g,
                                   (__attribute__((address_space(3))) void*)l, 16, 0, 0);
}

// raw workgroup barrier WITHOUT vmcnt/lgkmcnt drain; compiler memory fences on
// both sides so no LDS/global op is moved across it.
__device__ __forceinline__ void bar() {
  asm volatile("" ::: "memory");
  __builtin_amdgcn_s_barrier();
  asm volatile("" ::: "memory");
}

// bit-exact fp8 e4m3fn round-to-nearest-even; input must be pre-clipped to [-448,448]
__device__ __forceinline__ float fp8_e4m3_rne(float v) {
  float a = fabsf(v);
  float s = (v < 0.f) ? -1.f : 1.f;
  if (a < 0.015625f) {                 // below 2^-6: fp8 subnormal, quantum 2^-9
    float r = rintf(a * 512.0f);       // v_rndne = RNE
    return s * r * 0.001953125f;
  }
  uint32_t u = __float_as_uint(a);
  u = (u + 0x7FFFFu + ((u >> 20) & 1u)) & 0xFFF00000u;  // RNE to 3 mantissa bits
  return s * __uint_as_float(u);
}

__device__ __forceinline__ float block_sum256(float v) {
  __shared__ float sh[4];
  #pragma unroll
  for (int o = 32; o > 0; o >>= 1) v += __shfl_xor(v, o, 64);
  if ((threadIdx.x & 63) == 0) sh[threadIdx.x >> 6] = v;
  __syncthreads();
  return sh[0] + sh[1] + sh[2] + sh[3];
}

// ue8m0 scale: exp2(ceil(log2(max(amax,1e-10)/448))), emulating numpy fp32 semantics
__device__ __forceinline__ float ue8m0_scale(float amax) {
  float v = fmaxf(amax, 1e-10f) / 448.0f;
  float l = (float)log2((double)v);    // correctly-rounded; exact at powers of 2
  return exp2f(ceilf(l));
}

// ---------------- kernels ----------------

// w[z][k][n] f32 -> Wt[z][n][k] bf16, 64x64 tiles, vectorized both sides.
__global__ __launch_bounds__(256) void k_transpose_cast(const float* __restrict__ W,
                                                        bf16* __restrict__ Wt) {
  __shared__ float tile[64][65];
  const size_t mat = (size_t)HID * HID;
  const float* Wz = W + mat * blockIdx.z;
  bf16* Wtz = Wt + mat * blockIdx.z;
  int bn = blockIdx.x * 64;   // n base
  int bk = blockIdx.y * 64;   // k base
  int t = threadIdx.x;
  // load: tile[k][n] via float4, rows t>>4 (+16 per pass), cols (t&15)*4
  {
    int r = t >> 4, c = (t & 15) * 4;
    #pragma unroll
    for (int i = 0; i < 4; i++) {
      float4 v = *(const float4*)(Wz + (size_t)(bk + r + 16 * i) * HID + bn + c);
      tile[r + 16 * i][c] = v.x; tile[r + 16 * i][c + 1] = v.y;
      tile[r + 16 * i][c + 2] = v.z; tile[r + 16 * i][c + 3] = v.w;
    }
  }
  __syncthreads();
  // store: thread covers n = t>>2, k in [(t&3)*16, +16) -> two bf16x8 stores
  {
    int n = t >> 2, kc = (t & 3) * 16;
    bf16x8 o0, o1;
    #pragma unroll
    for (int j = 0; j < 8; j++) o0[j] = (bf16)tile[kc + j][n];
    #pragma unroll
    for (int j = 0; j < 8; j++) o1[j] = (bf16)tile[kc + 8 + j][n];
    bf16* dst = Wtz + (size_t)(bn + n) * HID + bk + kc;
    *(bf16x8*)dst = o0;
    *(bf16x8*)(dst + 8) = o1;
  }
}

// y = rmsnorm(relu(x)) * nw -> bf16 Y;  also write relu(x) -> bf16 R (residual).
// one block per row.
__global__ __launch_bounds__(256) void k_pre(const float* __restrict__ x,
                                             const float* __restrict__ nw,
                                             bf16* __restrict__ Y,
                                             bf16* __restrict__ R) {
  size_t base = (size_t)blockIdx.x * HID + threadIdx.x * 8;
  float4 v0 = *(const float4*)(x + base);
  float4 v1 = *(const float4*)(x + base + 4);
  float z[8] = {v0.x, v0.y, v0.z, v0.w, v1.x, v1.y, v1.z, v1.w};
  float ss = 0.f;
  #pragma unroll
  for (int i = 0; i < 8; i++) { z[i] = fmaxf(z[i], 0.f); ss += z[i] * z[i]; }
  float tot = block_sum256(ss);
  float s = rsqrtf(tot * (1.0f / HID) + EPSF);
  bf16x8 rr;
  #pragma unroll
  for (int i = 0; i < 8; i++) rr[i] = (bf16)z[i];
  *(bf16x8*)(R + base) = rr;
  int j0 = threadIdx.x * 8;
  float4 w0 = *(const float4*)(nw + j0);
  float4 w1 = *(const float4*)(nw + j0 + 4);
  float wv[8] = {w0.x, w0.y, w0.z, w0.w, w1.x, w1.y, w1.z, w1.w};
  bf16x8 o;
  #pragma unroll
  for (int i = 0; i < 8; i++) o[i] = (bf16)(z[i] * s * wv[i]);
  *(bf16x8*)(Y + base) = o;
}

// resid = residIn + Cin ; y = rmsnorm(resid)*nw ; per-128-group ue8m0 quant
// -> Aout (bf16 of fp8 values), scaleOut; residOut (bf16, may alias residIn).
// one block per row; thread t covers cols [t*8, t*8+8); group g = t>>4.
__global__ __launch_bounds__(256) void k_fuse_quant(const bf16* __restrict__ residIn,
                                                    const bf16* __restrict__ Cin,
                                                    const float* __restrict__ nw,
                                                    bf16* __restrict__ residOut,
                                                    bf16* __restrict__ Aout,
                                                    float* __restrict__ scaleOut) {
  int row = blockIdx.x;
  int j0 = threadIdx.x * 8;
  size_t base = (size_t)row * HID + j0;
  bf16x8 c  = *(const bf16x8*)(Cin + base);
  bf16x8 rv = *(const bf16x8*)(residIn + base);
  float r[8]; float ss = 0.f;
  #pragma unroll
  for (int i = 0; i < 8; i++) { r[i] = (float)rv[i] + (float)c[i]; ss += r[i] * r[i]; }
  float tot = block_sum256(ss);
  float s = rsqrtf(tot * (1.0f / HID) + EPSF);

  bf16x8 ro;
  #pragma unroll
  for (int i = 0; i < 8; i++) ro[i] = (bf16)r[i];
  *(bf16x8*)(residOut + base) = ro;

  float4 w0 = *(const float4*)(nw + j0);
  float4 w1 = *(const float4*)(nw + j0 + 4);
  float wv[8] = {w0.x, w0.y, w0.z, w0.w, w1.x, w1.y, w1.z, w1.w};
  float y[8], amax = 0.f;
  #pragma unroll
  for (int i = 0; i < 8; i++) { y[i] = r[i] * s * wv[i]; amax = fmaxf(amax, fabsf(y[i])); }
  // group = 128 cols = 16 consecutive threads (within one wave)
  amax = fmaxf(amax, __shfl_xor(amax, 1, 64));
  amax = fmaxf(amax, __shfl_xor(amax, 2, 64));
  amax = fmaxf(amax, __shfl_xor(amax, 4, 64));
  amax = fmaxf(amax, __shfl_xor(amax, 8, 64));
  float scale = ue8m0_scale(amax);
  float inv = 1.0f / scale;          // exact: scale is a power of 2
  bf16x8 q;
  #pragma unroll
  for (int i = 0; i < 8; i++) {
    float t = fminf(fmaxf(y[i] * inv, -448.f), 448.f);
    q[i] = (bf16)fp8_e4m3_rne(t);    // fp8 values are exact in bf16
  }
  *(bf16x8*)(Aout + base) = q;
  if ((threadIdx.x & 15) == 0) scaleOut[(size_t)row * NGRP + (j0 >> 7)] = scale;
}

// y4 = rmsnorm(residIn + Cin) * nw -> f32 out.  one block per row.
__global__ __launch_bounds__(256) void k_final(const bf16* __restrict__ residIn,
                                               const bf16* __restrict__ Cin,
                                               const float* __restrict__ nw,
                                               float* __restrict__ out) {
  size_t base = (size_t)blockIdx.x * HID + threadIdx.x * 8;
  bf16x8 c  = *(const bf16x8*)(Cin + base);
  bf16x8 rv = *(const bf16x8*)(residIn + base);
  float r[8]; float ss = 0.f;
  #pragma unroll
  for (int i = 0; i < 8; i++) { r[i] = (float)rv[i] + (float)c[i]; ss += r[i] * r[i]; }
  float tot = block_sum256(ss);
  float s = rsqrtf(tot * (1.0f / HID) + EPSF);
  int j0 = threadIdx.x * 8;
  float4 w0 = *(const float4*)(nw + j0);
  float4 w1 = *(const float4*)(nw + j0 + 4);
  float wv[8] = {w0.x, w0.y, w0.z, w0.w, w1.x, w1.y, w1.z, w1.w};
  float4 o0, o1;
  o0.x = r[0]*s*wv[0]; o0.y = r[1]*s*wv[1]; o0.z = r[2]*s*wv[2]; o0.w = r[3]*s*wv[3];
  o1.x = r[4]*s*wv[4]; o1.y = r[5]*s*wv[5]; o1.z = r[6]*s*wv[6]; o1.w = r[7]*s*wv[7];
  *(float4*)(out + base) = o0;
  *(float4*)(out + base + 4) = o1;
}

// C[M][N] = A[M][K] * B^T[N][K], bf16 in, fp32 acc, bf16 out.
// 256x256 tile, BK=32, 8 waves (2Mx4N), 4-slot LDS ring (128 KiB), staging runs
// 3 K-tiles ahead via global_load_lds w16, counted s_waitcnt vmcnt(8) (never 0
// in-loop), raw s_barrier (no drain), s_setprio around each 16-MFMA cluster.
// Swizzle: 16B chunk c of row r stored at slot c^((r>>1)&3); applied by
// pre-swizzling the global source (global_load_lds writes linearly) and reading
// with the same XOR -> 2-way bank sharing only (free).
// Grid mapping: bn = blockIdx&7 pins each XCD to one 256-col B panel (1 MiB,
// L2-resident); bm = blockIdx>>3.
__global__ __launch_bounds__(512, 2) void k_gemm(const bf16* __restrict__ A,
                                                 const bf16* __restrict__ B,
                                                 bf16* __restrict__ C,
                                                 int M, int N, int K) {
  // slot layout: slot*32768 | A: [0,16384) B: [16384,32768)
  // within A/B: row r (0..255) at r*64 bytes; chunk slots of 16 B XOR-swizzled
  __shared__ __align__(16) char lds[4 * 32768];
  int b = blockIdx.x;
  int bn = b & 7;            // XCD-local column panel
  int bm = b >> 3;
  int tid = threadIdx.x;
  int wave = tid >> 6, lane = tid & 63;
  int q = lane >> 4, rr = lane & 15;
  int wm = wave >> 2, wn = wave & 3;      // 2 x 4 wave grid, per-wave 128x64

  // staging source pointers (pre-swizzled): thread covers linear LDS chunk
  // m = i*512 + tid -> row r = m>>2, source chunk c = (m&3) ^ ((r>>1)&3)
  const bf16* aSrc[2]; const bf16* bSrc[2];
  #pragma unroll
  for (int i = 0; i < 2; i++) {
    int m = i * 512 + tid;
    int r = m >> 2;
    int c = (m & 3) ^ ((r >> 1) & 3);
    aSrc[i] = A + (size_t)(bm * 256 + r) * K + c * 8;
    bSrc[i] = B + (size_t)(bn * 256 + r) * K + c * 8;
  }

  // per-lane LDS read offset: row rr (within 16-row frag), k-chunk q, swizzled
  const int swz = (rr >> 1) & 3;
  const int ldoff = rr * 64 + ((q ^ swz) << 4);

  f32x4 acc[8][4];
  #pragma unroll
  for (int mf = 0; mf < 8; mf++)
    #pragma unroll
    for (int nf = 0; nf < 4; nf++)
      #pragma unroll
      for (int e = 0; e < 4; e++) acc[mf][nf][e] = 0.f;

  const int NT = K / 32;     // 64 K-tiles

  // prologue: stage tiles 0,1,2 into slots 0,1,2 (4 loads each: A0,A1,B0,B1)
  #pragma unroll
  for (int t = 0; t < 3; ++t) {
    char* db = lds + t * 32768 + wave * 1024;
    async_load16(aSrc[0] + t * 32, db);
    async_load16(aSrc[1] + t * 32, db + 8192);
    async_load16(bSrc[0] + t * 32, db + 16384);
    async_load16(bSrc[1] + t * 32, db + 16384 + 8192);
  }
  asm volatile("s_waitcnt vmcnt(8)" ::: "memory");   // tile 0 landed
  bar();

  for (int t = 0; t < NT; ++t) {
    const char* sb  = lds + (t & 3) * 32768;
    const char* rbA = sb + wm * 8192 + ldoff;            // wm*128 rows
    const char* rbB = sb + 16384 + wn * 4096 + ldoff;    // wn*64 rows
    const int u  = (t + 3 < NT) ? (t + 3) : (NT - 1);    // clamped: tail stages
    char* ub = lds + ((t + 3) & 3) * 32768 + wave * 1024;// land in dead slots

    // ---- phase 0: read B(all) + A(half 0); stage A(t+3); MFMA quadrant 0 ----
    bf16x8 bfr[4], afr[4];
    #pragma unroll
    for (int nf = 0; nf < 4; nf++)
      bfr[nf] = *(const bf16x8*)(rbB + nf * 1024);
    #pragma unroll
    for (int mf = 0; mf < 4; mf++)
      afr[mf] = *(const bf16x8*)(rbA + mf * 1024);
    async_load16(aSrc[0] + u * 32, ub);
    async_load16(aSrc[1] + u * 32, ub + 8192);
    bar();
    __builtin_amdgcn_s_setprio(1);
    #pragma unroll
    for (int mf = 0; mf < 4; mf++)
      #pragma unroll
      for (int nf = 0; nf < 4; nf++)
        acc[mf][nf] = __builtin_amdgcn_mfma_f32_16x16x32_bf16(afr[mf], bfr[nf], acc[mf][nf], 0, 0, 0);
    __builtin_amdgcn_s_setprio(0);
    bar();

    // ---- phase 1: read A(half 1); stage B(t+3); MFMA quadrant 1 ----
    #pragma unroll
    for (int mf = 0; mf < 4; mf++)
      afr[mf] = *(const bf16x8*)(rbA + 4096 + mf * 1024);
    async_load16(bSrc[0] + u * 32, ub + 16384);
    async_load16(bSrc[1] + u * 32, ub + 16384 + 8192);
    bar();
    __builtin_amdgcn_s_setprio(1);
    #pragma unroll
    for (int mf = 0; mf < 4; mf++)
      #pragma unroll
      for (int nf = 0; nf < 4; nf++)
        acc[4 + mf][nf] = __builtin_amdgcn_mfma_f32_16x16x32_bf16(afr[mf], bfr[nf], acc[4 + mf][nf], 0, 0, 0);
    __builtin_amdgcn_s_setprio(0);
    // checkpoint: allow tiles t+2,t+3 (8 loads) in flight; guarantees t+1 landed
    asm volatile("s_waitcnt vmcnt(8)" ::: "memory");
    bar();
  }

  // drain trailing (dead) stages before reusing vmem for stores
  asm volatile("s_waitcnt vmcnt(0)" ::: "memory");

  // epilogue: C/D layout col=lane&15, row=(lane>>4)*4+reg
  #pragma unroll
  for (int mf = 0; mf < 8; mf++)
    #pragma unroll
    for (int nf = 0; nf < 4; nf++)
      #pragma unroll
      for (int tt = 0; tt < 4; tt++) {
        int rowi = bm * 256 + wm * 128 + mf * 16 + q * 4 + tt;
        int coli = bn * 256 + wn * 64 + nf * 16 + rr;
        C[(size_t)rowi * N + coli] = (bf16)acc[mf][nf][tt];
      }
}

// ---------------- launch ----------------

extern "C" void kernel_launch(void* const* d_in, const int* in_sizes, int n_in,
                              void* d_out, int out_size, void* d_ws, size_t ws_size,
                              hipStream_t stream) {
  const float* x      = (const float*)d_in[0];
  const float* norm_w = (const float*)d_in[1];
  const float* w      = (const float*)d_in[2];

  float* out   = (float*)d_out;
  float* y4o   = out;
  float* s2o   = out + (size_t)NTOK * HID;           // y2_s [16384,16]
  float* s3o   = s2o + (size_t)NTOK * NGRP;          // y3_s [16384,16]

  char* ws = (char*)d_ws;
  const size_t WT_B = (size_t)3 * HID * HID * 2;     // 25,165,824
  const size_t AB_B = (size_t)NTOK * HID * 2;        // 67,108,864
  bf16* Wt   = (bf16*)ws;
  bf16* Abuf = (bf16*)(ws + WT_B);
  bf16* Cbuf = (bf16*)(ws + WT_B + AB_B);
  bf16* Rbuf = (bf16*)(ws + WT_B + 2 * AB_B);
  const size_t MATE = (size_t)HID * HID;

  dim3 gT(HID / 64, HID / 64, 3);
  int  gG = (NTOK / 256) * (HID / 256);    // 512 blocks, bn = b&7 (XCD panel)

  k_transpose_cast<<<gT, 256, 0, stream>>>(w, Wt);
  k_pre<<<NTOK, 256, 0, stream>>>(x, norm_w, Abuf, Rbuf);
  k_gemm<<<gG, 512, 0, stream>>>(Abuf, Wt, Cbuf, NTOK, HID, HID);
  k_fuse_quant<<<NTOK, 256, 0, stream>>>(Rbuf, Cbuf, norm_w + HID, Rbuf, Abuf, s2o);
  k_gemm<<<gG, 512, 0, stream>>>(Abuf, Wt + MATE, Cbuf, NTOK, HID, HID);
  k_fuse_quant<<<NTOK, 256, 0, stream>>>(Rbuf, Cbuf, norm_w + 2 * HID, Rbuf, Abuf, s3o);
  k_gemm<<<gG, 512, 0, stream>>>(Abuf, Wt + 2 * MATE, Cbuf, NTOK, HID, HID);
  k_final<<<NTOK, 256, 0, stream>>>(Rbuf, Cbuf, norm_w + 3 * HID, y4o);
}